// Round 1
// baseline (248.697 us; speedup 1.0000x reference)
//
#include <hip/hip_runtime.h>

#define D_DIM 1024
#define B_HALF 4096
#define NROWS 8192
#define INV_TEMP 10.0f

typedef __bf16 bf16x8 __attribute__((ext_vector_type(8)));
typedef float floatx4 __attribute__((ext_vector_type(4)));

__device__ __forceinline__ unsigned short f32_to_bf16(float f) {
    union { float f; unsigned u; } v; v.f = f;
    unsigned r = 0x7FFFu + ((v.u >> 16) & 1u);
    return (unsigned short)((v.u + r) >> 16);
}

// Kernel 1: L2-normalize rows of z1,z2 -> bf16 R [8192][1024]
__global__ __launch_bounds__(256) void normalize_kernel(
    const float* __restrict__ z1, const float* __restrict__ z2,
    unsigned short* __restrict__ R)
{
    const int row = blockIdx.x;
    const int tid = threadIdx.x;
    const float* src = (row < B_HALF) ? (z1 + (size_t)row * D_DIM)
                                      : (z2 + (size_t)(row - B_HALF) * D_DIM);
    float4 v = ((const float4*)src)[tid];
    float ss = v.x * v.x + v.y * v.y + v.z * v.z + v.w * v.w;
    #pragma unroll
    for (int off = 32; off > 0; off >>= 1) ss += __shfl_down(ss, off);
    __shared__ float wsum[4];
    if ((tid & 63) == 0) wsum[tid >> 6] = ss;
    __syncthreads();
    float tot = wsum[0] + wsum[1] + wsum[2] + wsum[3];
    float scale = 1.0f / fmaxf(sqrtf(tot), 1e-12f);
    ushort4 o;
    o.x = f32_to_bf16(v.x * scale);
    o.y = f32_to_bf16(v.y * scale);
    o.z = f32_to_bf16(v.z * scale);
    o.w = f32_to_bf16(v.w * scale);
    ((ushort4*)(R + (size_t)row * D_DIM))[tid] = o;
}

// Kernel 2: 128x128 tile of sim = R R^T * 10; per-row sum of exp (diag masked),
// capture pos where |r-c|==B_HALF. partial[row*64 + ct] = per-col-block row sum.
__global__ __launch_bounds__(256) void gemm_lse_kernel(
    const unsigned short* __restrict__ R,
    float* __restrict__ partial, float* __restrict__ pos)
{
    __shared__ unsigned short As[128 * 32];
    __shared__ unsigned short Bs[128 * 32];
    __shared__ float rowsum[2][128];

    const int ct = blockIdx.x, rt = blockIdx.y;
    const int tid = threadIdx.x;
    const int wave = tid >> 6, lane = tid & 63;
    const int wm = wave >> 1, wn = wave & 1;
    const int row0 = rt * 128, col0 = ct * 128;

    floatx4 acc[4][4] = {};

    const int lrow = lane >> 2;        // 0..15: tile row within 16-row chunk
    const int lk = (lane & 3) * 8;     // element offset within 32-elem K slab
    const unsigned short* gA = R + (size_t)row0 * D_DIM;
    const unsigned short* gB = R + (size_t)col0 * D_DIM;

    const int lm = lane & 15;
    const int lq = lane >> 4;          // 0..3

    for (int k0 = 0; k0 < D_DIM; k0 += 32) {
        #pragma unroll
        for (int rnd = 0; rnd < 2; ++rnd) {
            const int c = rnd * 4 + wave;        // chunk 0..7 (16 rows each)
            const int grow = c * 16 + lrow;
            __builtin_amdgcn_global_load_lds(
                (const __attribute__((address_space(1))) unsigned int*)(gA + (size_t)grow * D_DIM + k0 + lk),
                (__attribute__((address_space(3))) unsigned int*)(As + c * 512),
                16, 0, 0);
            __builtin_amdgcn_global_load_lds(
                (const __attribute__((address_space(1))) unsigned int*)(gB + (size_t)grow * D_DIM + k0 + lk),
                (__attribute__((address_space(3))) unsigned int*)(Bs + c * 512),
                16, 0, 0);
        }
        __syncthreads();

        bf16x8 af[4], bfr[4];
        #pragma unroll
        for (int i = 0; i < 4; ++i) {
            af[i]  = *(const bf16x8*)(As + (wm * 64 + i * 16 + lm) * 32 + lq * 8);
            bfr[i] = *(const bf16x8*)(Bs + (wn * 64 + i * 16 + lm) * 32 + lq * 8);
        }
        #pragma unroll
        for (int mi = 0; mi < 4; ++mi)
            #pragma unroll
            for (int ni = 0; ni < 4; ++ni)
                acc[mi][ni] = __builtin_amdgcn_mfma_f32_16x16x32_bf16(
                    af[mi], bfr[ni], acc[mi][ni], 0, 0, 0);
        __syncthreads();
    }

    // Epilogue: exp + masked row-sum + pos capture
    #pragma unroll
    for (int mi = 0; mi < 4; ++mi) {
        #pragma unroll
        for (int reg = 0; reg < 4; ++reg) {
            const int gr = row0 + wm * 64 + mi * 16 + lq * 4 + reg;
            float esum = 0.0f;
            #pragma unroll
            for (int ni = 0; ni < 4; ++ni) {
                const int gc = col0 + wn * 64 + ni * 16 + lm;
                float s = acc[mi][ni][reg] * INV_TEMP;
                if (gc == gr + B_HALF || gr == gc + B_HALF) pos[gr] = s;
                esum += (gc == gr) ? 0.0f : __expf(s);
            }
            esum += __shfl_xor(esum, 1);
            esum += __shfl_xor(esum, 2);
            esum += __shfl_xor(esum, 4);
            esum += __shfl_xor(esum, 8);
            if (lm == 0) rowsum[wn][wm * 64 + mi * 16 + lq * 4 + reg] = esum;
        }
    }
    __syncthreads();
    if (tid < 128) {
        partial[(size_t)(row0 + tid) * 64 + ct] = rowsum[0][tid] + rowsum[1][tid];
    }
}

// Kernel 3: S_r = sum of 64 partials; loss = mean(log1p(S * exp(-pos)))
__global__ __launch_bounds__(256) void finalize_kernel(
    const float* __restrict__ partial, const float* __restrict__ pos,
    float* __restrict__ out)
{
    const int r = blockIdx.x * 256 + threadIdx.x;
    const float4* p = (const float4*)(partial + (size_t)r * 64);
    float S = 0.0f;
    #pragma unroll
    for (int i = 0; i < 16; ++i) { float4 v = p[i]; S += (v.x + v.y) + (v.z + v.w); }
    const float po = pos[r];
    float contrib = log1pf(S * __expf(-po));
    #pragma unroll
    for (int off = 32; off > 0; off >>= 1) contrib += __shfl_down(contrib, off);
    __shared__ float wsum[4];
    if ((threadIdx.x & 63) == 0) wsum[threadIdx.x >> 6] = contrib;
    __syncthreads();
    if (threadIdx.x == 0)
        atomicAdd(out, (wsum[0] + wsum[1] + wsum[2] + wsum[3]) * (1.0f / 8192.0f));
}

extern "C" void kernel_launch(void* const* d_in, const int* in_sizes, int n_in,
                              void* d_out, int out_size, void* d_ws, size_t ws_size,
                              hipStream_t stream)
{
    const float* z1 = (const float*)d_in[0];
    const float* z2 = (const float*)d_in[1];
    float* out = (float*)d_out;
    char* ws = (char*)d_ws;
    unsigned short* R = (unsigned short*)ws;                      // 16 MiB bf16 reps
    float* partial = (float*)(ws + (size_t)16 * 1024 * 1024);     // 2 MiB [8192][64]
    float* pos     = (float*)(ws + (size_t)18 * 1024 * 1024);     // 32 KiB [8192]

    hipMemsetAsync(d_out, 0, sizeof(float), stream);
    normalize_kernel<<<NROWS, 256, 0, stream>>>(z1, z2, R);
    gemm_lse_kernel<<<dim3(64, 64), 256, 0, stream>>>(R, partial, pos);
    finalize_kernel<<<32, 256, 0, stream>>>(partial, pos, out);
}

// Round 2
// 174.666 us; speedup vs baseline: 1.4238x; 1.4238x over previous
//
#include <hip/hip_runtime.h>

#define D_DIM 1024
#define B_HALF 4096
#define NROWS 8192
#define INV_TEMP 10.0f

typedef __bf16 bf16x8 __attribute__((ext_vector_type(8)));
typedef float floatx4 __attribute__((ext_vector_type(4)));

__device__ __forceinline__ unsigned short f32_to_bf16(float f) {
    union { float f; unsigned u; } v; v.f = f;
    unsigned r = 0x7FFFu + ((v.u >> 16) & 1u);
    return (unsigned short)((v.u + r) >> 16);
}

// Kernel 1: L2-normalize rows of z1,z2 -> bf16 R [8192][1024]
__global__ __launch_bounds__(256) void normalize_kernel(
    const float* __restrict__ z1, const float* __restrict__ z2,
    unsigned short* __restrict__ R)
{
    const int row = blockIdx.x;
    const int tid = threadIdx.x;
    const float* src = (row < B_HALF) ? (z1 + (size_t)row * D_DIM)
                                      : (z2 + (size_t)(row - B_HALF) * D_DIM);
    float4 v = ((const float4*)src)[tid];
    float ss = v.x * v.x + v.y * v.y + v.z * v.z + v.w * v.w;
    #pragma unroll
    for (int off = 32; off > 0; off >>= 1) ss += __shfl_down(ss, off);
    __shared__ float wsum[4];
    if ((tid & 63) == 0) wsum[tid >> 6] = ss;
    __syncthreads();
    float tot = wsum[0] + wsum[1] + wsum[2] + wsum[3];
    float scale = 1.0f / fmaxf(sqrtf(tot), 1e-12f);
    ushort4 o;
    o.x = f32_to_bf16(v.x * scale);
    o.y = f32_to_bf16(v.y * scale);
    o.z = f32_to_bf16(v.z * scale);
    o.w = f32_to_bf16(v.w * scale);
    ((ushort4*)(R + (size_t)row * D_DIM))[tid] = o;
}

// Kernel 2 (symmetric): only upper-triangular tile pairs (rt <= ct).
// Off-diag block contributes row sums to rows [row0,row0+128) at slot ct AND
// column sums (== transposed row sums by symmetry) to rows [col0,col0+128)
// at slot rt. Diagonal blocks mask j==i and contribute row sums only.
__global__ __launch_bounds__(256) void gemm_lse_kernel(
    const unsigned short* __restrict__ R,
    float* __restrict__ partial, float* __restrict__ pos)
{
    __shared__ unsigned short As[128 * 32];
    __shared__ unsigned short Bs[128 * 32];
    __shared__ float rowsum[2][128];
    __shared__ float colsum[2][128];

    // decode linear block id -> (rt, ct) with rt <= ct, rt-major ordering
    const int t = blockIdx.x;
    int rt = (int)((129.0f - sqrtf((float)(16641 - 8 * t))) * 0.5f);
    while ((rt + 1) * 64 - (rt + 1) * rt / 2 <= t) ++rt;   // fixup (fp safety)
    while (rt * 64 - rt * (rt - 1) / 2 > t) --rt;
    const int ct = rt + (t - (rt * 64 - rt * (rt - 1) / 2));
    const bool isDiag = (rt == ct);

    const int tid = threadIdx.x;
    const int wave = tid >> 6, lane = tid & 63;
    const int wm = wave >> 1, wn = wave & 1;
    const int row0 = rt * 128, col0 = ct * 128;

    floatx4 acc[4][4] = {};

    const int lrow = lane >> 2;        // 0..15: tile row within 16-row chunk
    const int lk = (lane & 3) * 8;     // element offset within 32-elem K slab
    const unsigned short* gA = R + (size_t)row0 * D_DIM;
    const unsigned short* gB = R + (size_t)col0 * D_DIM;

    const int lm = lane & 15;
    const int lq = lane >> 4;          // 0..3

    for (int k0 = 0; k0 < D_DIM; k0 += 32) {
        #pragma unroll
        for (int rnd = 0; rnd < 2; ++rnd) {
            const int c = rnd * 4 + wave;        // chunk 0..7 (16 rows each)
            const int grow = c * 16 + lrow;
            __builtin_amdgcn_global_load_lds(
                (const __attribute__((address_space(1))) unsigned int*)(gA + (size_t)grow * D_DIM + k0 + lk),
                (__attribute__((address_space(3))) unsigned int*)(As + c * 512),
                16, 0, 0);
            __builtin_amdgcn_global_load_lds(
                (const __attribute__((address_space(1))) unsigned int*)(gB + (size_t)grow * D_DIM + k0 + lk),
                (__attribute__((address_space(3))) unsigned int*)(Bs + c * 512),
                16, 0, 0);
        }
        __syncthreads();

        bf16x8 af[4], bfr[4];
        #pragma unroll
        for (int i = 0; i < 4; ++i) {
            af[i]  = *(const bf16x8*)(As + (wm * 64 + i * 16 + lm) * 32 + lq * 8);
            bfr[i] = *(const bf16x8*)(Bs + (wn * 64 + i * 16 + lm) * 32 + lq * 8);
        }
        #pragma unroll
        for (int mi = 0; mi < 4; ++mi)
            #pragma unroll
            for (int ni = 0; ni < 4; ++ni)
                acc[mi][ni] = __builtin_amdgcn_mfma_f32_16x16x32_bf16(
                    af[mi], bfr[ni], acc[mi][ni], 0, 0, 0);
        __syncthreads();
    }

    // Epilogue: exp once per element; accumulate row sums AND col sums.
    float ecol[4] = {0.0f, 0.0f, 0.0f, 0.0f};
    #pragma unroll
    for (int mi = 0; mi < 4; ++mi) {
        #pragma unroll
        for (int reg = 0; reg < 4; ++reg) {
            const int gr = row0 + wm * 64 + mi * 16 + lq * 4 + reg;
            float esum = 0.0f;
            #pragma unroll
            for (int ni = 0; ni < 4; ++ni) {
                const int gc = col0 + wn * 64 + ni * 16 + lm;
                float s = acc[mi][ni][reg] * INV_TEMP;
                if (gc == gr + B_HALF) { pos[gr] = s; pos[gc] = s; }
                float e = (gc == gr) ? 0.0f : __expf(s);
                esum += e;
                ecol[ni] += e;
            }
            esum += __shfl_xor(esum, 1);
            esum += __shfl_xor(esum, 2);
            esum += __shfl_xor(esum, 4);
            esum += __shfl_xor(esum, 8);
            if (lm == 0) rowsum[wn][wm * 64 + mi * 16 + lq * 4 + reg] = esum;
        }
    }
    #pragma unroll
    for (int ni = 0; ni < 4; ++ni) {
        ecol[ni] += __shfl_xor(ecol[ni], 16);
        ecol[ni] += __shfl_xor(ecol[ni], 32);
    }
    if (lq == 0 && !isDiag) {
        #pragma unroll
        for (int ni = 0; ni < 4; ++ni)
            colsum[wm][wn * 64 + ni * 16 + lm] = ecol[ni];
    }
    __syncthreads();
    if (tid < 128) {
        partial[(size_t)(row0 + tid) * 64 + ct] = rowsum[0][tid] + rowsum[1][tid];
        if (!isDiag)
            partial[(size_t)(col0 + tid) * 64 + rt] = colsum[0][tid] + colsum[1][tid];
    }
}

// Kernel 3: S_r = sum of 64 partials; loss = mean(log1p(S * exp(-pos)))
__global__ __launch_bounds__(256) void finalize_kernel(
    const float* __restrict__ partial, const float* __restrict__ pos,
    float* __restrict__ out)
{
    const int r = blockIdx.x * 256 + threadIdx.x;
    const float4* p = (const float4*)(partial + (size_t)r * 64);
    float S = 0.0f;
    #pragma unroll
    for (int i = 0; i < 16; ++i) { float4 v = p[i]; S += (v.x + v.y) + (v.z + v.w); }
    const float po = pos[r];
    float contrib = log1pf(S * __expf(-po));
    #pragma unroll
    for (int off = 32; off > 0; off >>= 1) contrib += __shfl_down(contrib, off);
    __shared__ float wsum[4];
    if ((threadIdx.x & 63) == 0) wsum[threadIdx.x >> 6] = contrib;
    __syncthreads();
    if (threadIdx.x == 0)
        atomicAdd(out, (wsum[0] + wsum[1] + wsum[2] + wsum[3]) * (1.0f / 8192.0f));
}

extern "C" void kernel_launch(void* const* d_in, const int* in_sizes, int n_in,
                              void* d_out, int out_size, void* d_ws, size_t ws_size,
                              hipStream_t stream)
{
    const float* z1 = (const float*)d_in[0];
    const float* z2 = (const float*)d_in[1];
    float* out = (float*)d_out;
    char* ws = (char*)d_ws;
    unsigned short* R = (unsigned short*)ws;                      // 16 MiB bf16 reps
    float* partial = (float*)(ws + (size_t)16 * 1024 * 1024);     // 2 MiB [8192][64]
    float* pos     = (float*)(ws + (size_t)18 * 1024 * 1024);     // 32 KiB [8192]

    hipMemsetAsync(d_out, 0, sizeof(float), stream);
    normalize_kernel<<<NROWS, 256, 0, stream>>>(z1, z2, R);
    gemm_lse_kernel<<<2080, 256, 0, stream>>>(R, partial, pos);   // 64*65/2 upper-tri tiles
    finalize_kernel<<<32, 256, 0, stream>>>(partial, pos, out);
}